// Round 7
// baseline (312.249 us; speedup 1.0000x reference)
//
#include <hip/hip_runtime.h>
#include <hip/hip_fp16.h>
#include <math.h>

typedef _Float16 half8   __attribute__((ext_vector_type(8)));
typedef _Float16 half2v  __attribute__((ext_vector_type(2)));
typedef float    floatx16 __attribute__((ext_vector_type(16)));

#define ROWS   16384
#define DIM    128
#define KCODES 8192
#define NSPLIT 4
#define SPLITK (KCODES / NSPLIT)   // 2048
#define NCH    (SPLITK / 32)       // 64 chunks of 32 codes
#define LOSS_SCALE (1.0f / ((float)ROWS * (float)DIM))

// ---------------- kernel 1a: codebook prep -> interleaved [code][hi128|lo128] ----
__global__ __launch_bounds__(256) void prep_cb(
    const float* __restrict__ cb, _Float16* __restrict__ cbs,
    float* __restrict__ e2g)
{
  int tid = threadIdx.x;
  int L = tid & 63;
  int row = blockIdx.x * 4 + (tid >> 6);
  float2 v = ((const float2*)(cb + (size_t)row * DIM))[L];
  float s2 = v.x * v.x + v.y * v.y;
  #pragma unroll
  for (int m = 1; m < 64; m <<= 1) s2 += __shfl_xor(s2, m);
  if (L == 0) e2g[row] = -0.5f * s2;          // pre-scaled for t = dot - e2/2
  _Float16 h0 = (_Float16)v.x, h1 = (_Float16)v.y;
  half2v hi = {h0, h1};
  half2v lo = {(_Float16)(v.x - (float)h0), (_Float16)(v.y - (float)h1)};
  _Float16* dst = cbs + (size_t)row * 256;
  ((half2v*)dst)[L] = hi;
  ((half2v*)(dst + 128))[L] = lo;
}

// ---------------- kernel 1b: x prep -> LN + split -> [row][hi128|lo128] + x2 ----
__global__ __launch_bounds__(256) void prep_x(
    const float* __restrict__ x, _Float16* __restrict__ xs,
    float* __restrict__ x2g)
{
  int tid = threadIdx.x;
  int L = tid & 63;
  int row = blockIdx.x * 4 + (tid >> 6);
  float2 v = ((const float2*)(x + (size_t)row * DIM))[L];
  float s = v.x + v.y;
  #pragma unroll
  for (int m = 1; m < 64; m <<= 1) s += __shfl_xor(s, m);
  float mu = s * (1.0f / 128.0f);
  float dx = v.x - mu, dy = v.y - mu;
  float s2 = dx * dx + dy * dy;
  #pragma unroll
  for (int m = 1; m < 64; m <<= 1) s2 += __shfl_xor(s2, m);
  float rstd = 1.0f / sqrtf(s2 * (1.0f / 128.0f) + 1e-5f);
  float xn0 = dx * rstd, xn1 = dy * rstd;
  float x2 = xn0 * xn0 + xn1 * xn1;
  #pragma unroll
  for (int m = 1; m < 64; m <<= 1) x2 += __shfl_xor(x2, m);
  if (L == 0) x2g[row] = x2;                  // ||xn||^2 (for loss)
  _Float16 h0 = (_Float16)xn0, h1 = (_Float16)xn1;
  half2v hi = {h0, h1};
  half2v lo = {(_Float16)(xn0 - (float)h0), (_Float16)(xn1 - (float)h1)};
  _Float16* dst = xs + (size_t)row * 256;
  ((half2v*)dst)[L] = hi;
  ((half2v*)(dst + 128))[L] = lo;
}

// ---------------- kernel 2: argmin, barrier-free L2-streaming ----------------
// R3-R6 evidence: every LDS-staged barriered K-loop plateaus at MfmaUtil 35-48%
// (per-chunk __syncthreads gang-stalls all waves; MFMA+LDS+VALU serialize into
// the wall instead of overlapping). Here each lane streams ITS code column
// (B[n=col][k]) directly from the interleaved codebook split: one 64b pointer
// + immediate offsets, no LDS staging, no per-chunk barrier. 8 waves/CU
// free-run and oversubscribe the matrix pipe. (256,2) caps regs at 256 under
// both launch_bounds semantics.
__global__ __launch_bounds__(256, 2) void argmin_kernel(
    const _Float16* __restrict__ xs, const _Float16* __restrict__ cbs,
    const float* __restrict__ e2g, float* __restrict__ best_part,
    int* __restrict__ idx_part)
{
  __shared__ float e2s[SPLITK];   // 8 KB, staged once

  int tid = threadIdx.x;
  int w   = tid >> 6;
  int L   = tid & 63;
  int col = L & 31;      // A-row m / B-code n / D-col lane index
  int kh  = L >> 5;      // k-half

  int mt = blockIdx.x & 127;
  int ns = blockIdx.x >> 7;            // 0..3
  int code0 = ns * SPLITK;

  for (int i = tid; i < SPLITK; i += 256) e2s[i] = e2g[code0 + i];

  int rowbase = mt * 128 + w * 32;

  // A-fragments: lane holds rows rowbase+col, dims ks*16 + kh*8 + j
  const _Float16* xa = xs + (size_t)(rowbase + col) * 256 + kh * 8;
  half8 ah[8], al[8];
  #pragma unroll
  for (int ks = 0; ks < 8; ++ks) {
    ah[ks] = *(const half8*)(xa + ks * 16);
    al[ks] = *(const half8*)(xa + 128 + ks * 16);
  }

  float best[16]; int bch[16];
  #pragma unroll
  for (int r = 0; r < 16; ++r) { best[r] = -3.4e38f; bch[r] = 0; }

  // B stream: lane's code = code0 + ch*32 + col; 16 loads/chunk at imm offsets
  const _Float16* bp = cbs + (size_t)(code0 + col) * 256 + kh * 8;

  __syncthreads();   // e2s ready (the only barrier)

  #pragma unroll 1
  for (int ch = 0; ch < NCH; ++ch) {
    half8 bh[8], bl[8];
    #pragma unroll
    for (int ks = 0; ks < 8; ++ks) {
      bh[ks] = *(const half8*)(bp + ks * 16);
      bl[ks] = *(const half8*)(bp + 128 + ks * 16);
    }
    float e2f = e2s[ch * 32 + col];    // -e2/2 of this lane's code

    floatx16 a0 = {0,0,0,0,0,0,0,0,0,0,0,0,0,0,0,0};
    floatx16 a1 = {0,0,0,0,0,0,0,0,0,0,0,0,0,0,0,0};
    #pragma unroll
    for (int ks = 0; ks < 8; ++ks) {
      a0 = __builtin_amdgcn_mfma_f32_32x32x16_f16(ah[ks], bh[ks], a0, 0, 0, 0);
      a1 = __builtin_amdgcn_mfma_f32_32x32x16_f16(ah[ks], bl[ks], a1, 0, 0, 0);
      a1 = __builtin_amdgcn_mfma_f32_32x32x16_f16(al[ks], bh[ks], a1, 0, 0, 0);
    }
    #pragma unroll
    for (int r = 0; r < 16; ++r) {
      float t = (a0[r] + a1[r]) + e2f;   // t = dot - e2/2 (maximize)
      if (t > best[r]) { best[r] = t; bch[r] = ch; }
    }
    bp += 32 * 256;
  }

  // reduce over 32 code-column lanes; max-t, ties -> smaller index
  int ibase = code0 + col;
  #pragma unroll
  for (int r = 0; r < 16; ++r) {
    float b = best[r];
    int   bi = (bch[r] << 5) + ibase;
    #pragma unroll
    for (int m = 1; m < 32; m <<= 1) {
      float ob = __shfl_xor(b, m);
      int   oi = __shfl_xor(bi, m);
      if (ob > b || (ob == b && oi < bi)) { b = ob; bi = oi; }
    }
    if (col == 0) {
      int rw = rowbase + (r & 3) + ((r >> 2) << 3) + (kh << 2);
      best_part[(size_t)rw * NSPLIT + ns] = b;
      idx_part [(size_t)rw * NSPLIT + ns] = bi;
    }
  }
}

// ---------------- kernel 3: merge + gather + per-block loss partial ----------
// 64 rows/block. loss per row = ||xn||^2 - 2*t_best.
__global__ __launch_bounds__(256) void gather_loss_kernel(
    const float* __restrict__ cb, const float* __restrict__ best_part,
    const int* __restrict__ idx_part, const float* __restrict__ x2g,
    float* __restrict__ out_q, float* __restrict__ out_ind,
    float* __restrict__ loss_part)
{
  __shared__ int   sidx[64];
  __shared__ float sloss[64];
  int tid = threadIdx.x;
  int rb = blockIdx.x * 64;
  int r = tid >> 2, k = tid & 3;
  int row = rb + r;

  float b  = best_part[(size_t)row * NSPLIT + k];
  int   bi = idx_part [(size_t)row * NSPLIT + k];
  #pragma unroll
  for (int m = 1; m < 4; m <<= 1) {
    float ob = __shfl_xor(b, m);
    int   oi = __shfl_xor(bi, m);
    if (ob > b || (ob == b && oi < bi)) { b = ob; bi = oi; }
  }
  if (k == 0) {
    sidx[r] = bi;
    out_ind[row] = (float)bi;
    sloss[r] = x2g[row] - 2.0f * b;
  }
  __syncthreads();

  if (tid < 64) {
    float sl = sloss[tid];
    #pragma unroll
    for (int m = 1; m < 64; m <<= 1) sl += __shfl_xor(sl, m);
    if (tid == 0) loss_part[blockIdx.x] = sl;
  }

  // copy 64 codebook rows (512B each) to out_q
  const float4* cb4 = (const float4*)cb;
  float4* oq4 = (float4*)out_q;
  #pragma unroll
  for (int it = 0; it < 8; ++it) {
    int idx = it * 256 + tid;          // 0..2047
    int r2 = idx >> 5, c4 = idx & 31;
    oq4[(size_t)(rb + r2) * 32 + c4] = cb4[(size_t)sidx[r2] * 32 + c4];
  }
}

// ---------------- kernel 4: deterministic loss reduction (256 partials) ------
__global__ __launch_bounds__(256) void loss_reduce_kernel(
    const float* __restrict__ loss_part, float* __restrict__ out_loss)
{
  __shared__ float sm[256];
  int tid = threadIdx.x;
  sm[tid] = loss_part[tid];
  __syncthreads();
  for (int st = 128; st > 0; st >>= 1) {
    if (tid < st) sm[tid] += sm[tid + st];
    __syncthreads();
  }
  if (tid == 0) *out_loss = sm[0] * LOSS_SCALE;
}

extern "C" void kernel_launch(void* const* d_in, const int* in_sizes, int n_in,
                              void* d_out, int out_size, void* d_ws, size_t ws_size,
                              hipStream_t stream)
{
  const float* x  = (const float*)d_in[0];   // [4,4096,128] fp32
  const float* cb = (const float*)d_in[1];   // [8192,128]  fp32

  char* ws = (char*)d_ws;
  _Float16* cbs      = (_Float16*)(ws + 0);          // 4 MB  [code][hi128|lo128]
  float*    e2g      = (float*)   (ws + 4194304);    // 32 KB (-e2/2)
  float*    best_part= (float*)   (ws + 4227072);    // 256 KB
  int*      idx_part = (int*)     (ws + 4489216);    // 256 KB
  float*    x2g      = (float*)   (ws + 4751360);    // 64 KB
  float*    loss_part= (float*)   (ws + 4816896);    // 1 KB

  float* out_q    = (float*)d_out;                   // 16384*128
  float* out_ind  = out_q + (size_t)ROWS * DIM;      // 16384 (as float)
  float* out_loss = out_ind + ROWS;                  // 1

  // xs (LN'd x, split hi/lo, 8 MB) lives in the out_q region: argmin reads it,
  // then gather_loss overwrites the region with the final quantize output.
  _Float16* xs = (_Float16*)out_q;

  prep_cb<<<KCODES / 4, 256, 0, stream>>>(cb, cbs, e2g);
  prep_x <<<ROWS / 4,  256, 0, stream>>>(x, xs, x2g);
  argmin_kernel<<<128 * NSPLIT, 256, 0, stream>>>(xs, cbs, e2g, best_part, idx_part);
  gather_loss_kernel<<<ROWS / 64, 256, 0, stream>>>(cb, best_part, idx_part, x2g, out_q, out_ind, loss_part);
  loss_reduce_kernel<<<1, 256, 0, stream>>>(loss_part, out_loss);
}

// Round 8
// 162.574 us; speedup vs baseline: 1.9207x; 1.9207x over previous
//
#include <hip/hip_runtime.h>
#include <hip/hip_fp16.h>
#include <math.h>

typedef _Float16 half8  __attribute__((ext_vector_type(8)));
typedef _Float16 half2v __attribute__((ext_vector_type(2)));
typedef float   floatx4 __attribute__((ext_vector_type(4)));

#define ROWS   16384
#define DIM    128
#define KCODES 8192
#define NSPLIT 8
#define MTILE  256          // 4 waves x 4 groups x 16 rows
#define NT     64
#define SPLITK (KCODES / NSPLIT)
#define NCHUNK (SPLITK / NT)   // 16
#define LOSS_SCALE (1.0f / ((float)ROWS * (float)DIM))

__device__ __forceinline__ void async_copy16(const _Float16* src, _Float16* dst_lds) {
  __builtin_amdgcn_global_load_lds((const __attribute__((address_space(1))) void*)src,
                                   (__attribute__((address_space(3))) void*)dst_lds,
                                   16, 0, 0);
}

// ---------------- kernel 1: codebook prep (fp16 hi/lo split + (-e2/2)) --------
__global__ __launch_bounds__(256) void prep_codebook(
    const float* __restrict__ cb, _Float16* __restrict__ ehg,
    _Float16* __restrict__ elg, float* __restrict__ e2g,
    float* __restrict__ out_loss)
{
  int tid = threadIdx.x;
  if (blockIdx.x == 0 && tid == 0) *out_loss = 0.f;   // gather accumulates
  int L = tid & 63;
  int row = blockIdx.x * 4 + (tid >> 6);
  float2 v = ((const float2*)(cb + (size_t)row * DIM))[L];
  float s2 = v.x * v.x + v.y * v.y;
  #pragma unroll
  for (int m = 1; m < 64; m <<= 1) s2 += __shfl_xor(s2, m);
  if (L == 0) e2g[row] = -0.5f * s2;      // pre-scaled for t = dot - e2/2
  _Float16 h0 = (_Float16)v.x, h1 = (_Float16)v.y;
  half2v hi = {h0, h1};
  half2v lo = {(_Float16)(v.x - (float)h0), (_Float16)(v.y - (float)h1)};
  ((half2v*)(ehg + (size_t)row * DIM))[L] = hi;
  ((half2v*)(elg + (size_t)row * DIM))[L] = lo;
}

// ---------------- kernel 2: LN + argmin via split-fp16 MFMA ----------------
// R4/R5 structure (g=4 row-groups/wave: 8 ds_read_b128 feed 48 MFMAs, LDS pipe
// ~40% of MFMA pipe) but with a 4-WAVE block (MTILE=256) and 64 KB LDS so TWO
// independent blocks co-reside per CU: one block's MFMA covers the other's
// __syncthreads drain (R4/R5 evidence: single resident block gang-stalls at
// every barrier, pinning MfmaUtil at 45%; R6/R7 evidence: cutting g or LDS
// staging saturates LDS/L2 instead). (256,2) caps regs at 256 under both
// launch_bounds semantics; 2 x 65536 B LDS = 131 KB <= 160 KB.
__global__ __launch_bounds__(256, 2) void argmin_kernel(
    const float* __restrict__ x, const _Float16* __restrict__ ehg,
    const _Float16* __restrict__ elg, const float* __restrict__ e2g,
    float* __restrict__ best_part, int* __restrict__ idx_part,
    float* __restrict__ x2g)
{
  // [buf][arr(hi/lo)][code n][128 halfs]; 16B chunk at slot kcs holds global
  // chunk kcs ^ (n&7). 64 KB.
  __shared__ _Float16 ebuf[2][2][64][128];

  int tid = threadIdx.x;
  int w   = tid >> 6;
  int L   = tid & 63;
  int c   = L & 15;      // MFMA A-row / B-col lane index
  int q   = L >> 4;      // quad

  int bx = blockIdx.x;
  int mt = bx & 63;                   // 0..63
  int ns = bx >> 6;                   // 0..7
  int code0 = ns * SPLITK;

  int rowbase = mt * MTILE + w * 64;

  half8 ah[4][4], al[4][4];

  #pragma unroll
  for (int g = 0; g < 4; ++g) {
    const float* xr = x + (size_t)(rowbase + g * 16 + c) * DIM;
    float v[32];
    #pragma unroll
    for (int ks = 0; ks < 4; ++ks) {
      float4 p0 = *(const float4*)(xr + ks * 32 + q * 8);
      float4 p1 = *(const float4*)(xr + ks * 32 + q * 8 + 4);
      v[ks*8+0] = p0.x; v[ks*8+1] = p0.y; v[ks*8+2] = p0.z; v[ks*8+3] = p0.w;
      v[ks*8+4] = p1.x; v[ks*8+5] = p1.y; v[ks*8+6] = p1.z; v[ks*8+7] = p1.w;
    }
    float s = 0.f;
    #pragma unroll
    for (int i = 0; i < 32; ++i) s += v[i];
    s += __shfl_xor(s, 16); s += __shfl_xor(s, 32);
    float mu = s * (1.0f / 128.0f);
    float s2 = 0.f;
    #pragma unroll
    for (int i = 0; i < 32; ++i) { float d = v[i] - mu; s2 += d * d; }
    s2 += __shfl_xor(s2, 16); s2 += __shfl_xor(s2, 32);
    float rstd = 1.0f / sqrtf(s2 * (1.0f / 128.0f) + 1e-5f);
    float x2 = 0.f;
    #pragma unroll
    for (int ks = 0; ks < 4; ++ks)
      #pragma unroll
      for (int j = 0; j < 8; ++j) {
        float xv = (v[ks*8+j] - mu) * rstd;
        x2 += xv * xv;
        _Float16 h = (_Float16)xv;
        ah[g][ks][j] = h;
        al[g][ks][j] = (_Float16)(xv - (float)h);
      }
    x2 += __shfl_xor(x2, 16); x2 += __shfl_xor(x2, 32);
    if (ns == 0 && q == 0) x2g[rowbase + g * 16 + c] = x2;  // ||xn||^2 for loss
  }

  // track t = dot - e2/2 (maximize); ties -> smaller index
  float best[4][4]; int bidx[4][4];
  #pragma unroll
  for (int g = 0; g < 4; ++g)
    #pragma unroll
    for (int r = 0; r < 4; ++r) { best[g][r] = -3.4e38f; bidx[g][r] = 0; }

  _Float16* lbase = &ebuf[0][0][0][0];

  // ---- async staging: 2048 16B chunks per tile, 8 per thread ----
  auto stage = [&](int ch, int p) {
    int cbase = code0 + ch * NT;
    _Float16* lb = lbase + (size_t)p * 2 * 64 * 128;
    #pragma unroll
    for (int it = 0; it < 8; ++it) {
      int cid = it * 256 + tid;          // 0..2047
      int arr = cid >> 10;               // 0 = hi, 1 = lo
      int lc  = cid & 1023;
      int n   = lc >> 4;
      int kcs = lc & 15;                 // LDS slot chunk
      int kc  = kcs ^ (n & 7);           // global chunk (inverse swizzle)
      const _Float16* g = (arr ? elg : ehg) + (size_t)(cbase + n) * DIM + kc * 8;
      async_copy16(g, lb + (size_t)cid * 8);
    }
  };

  // e2 prefetch for chunk 0
  float e2n[4];
  #pragma unroll
  for (int s = 0; s < 4; ++s) e2n[s] = e2g[code0 + s * 16 + c];

  stage(0, 0);
  __syncthreads();

  for (int ch = 0; ch < NCHUNK; ++ch) {
    int p = ch & 1;
    int cbase = code0 + ch * NT;
    if (ch + 1 < NCHUNK) stage(ch + 1, p ^ 1);

    float e2h[4];
    #pragma unroll
    for (int s = 0; s < 4; ++s) e2h[s] = e2n[s];
    if (ch + 1 < NCHUNK) {
      #pragma unroll
      for (int s = 0; s < 4; ++s) e2n[s] = e2g[cbase + NT + s * 16 + c];
    }

    #pragma unroll
    for (int s = 0; s < 4; ++s) {
      int n = s * 16 + c;                // n & 7 == c & 7
      half8 bh[4], bl[4];
      #pragma unroll
      for (int ks = 0; ks < 4; ++ks) {
        int slot = ((ks * 4 + q) ^ (c & 7)) * 8;
        bh[ks] = *(const half8*)&ebuf[p][0][n][slot];
        bl[ks] = *(const half8*)&ebuf[p][1][n][slot];
      }
      int nn = cbase + n;
      #pragma unroll
      for (int g = 0; g < 4; ++g) {
        floatx4 acc = {e2h[s], e2h[s], e2h[s], e2h[s]};
        #pragma unroll
        for (int ks = 0; ks < 4; ++ks) {
          acc = __builtin_amdgcn_mfma_f32_16x16x32_f16(ah[g][ks], bh[ks], acc, 0, 0, 0);
          acc = __builtin_amdgcn_mfma_f32_16x16x32_f16(ah[g][ks], bl[ks], acc, 0, 0, 0);
          acc = __builtin_amdgcn_mfma_f32_16x16x32_f16(al[g][ks], bh[ks], acc, 0, 0, 0);
        }
        #pragma unroll
        for (int r = 0; r < 4; ++r) {
          float t = acc[r];
          if (t > best[g][r]) { best[g][r] = t; bidx[g][r] = nn; }
        }
      }
    }
    __syncthreads();   // drains async stage of ch+1; protects buf reuse
  }

  // reduce over the 16 col-lanes of each quad; max-t, ties -> smaller index
  #pragma unroll
  for (int m = 1; m < 16; m <<= 1)
    #pragma unroll
    for (int g = 0; g < 4; ++g)
      #pragma unroll
      for (int r = 0; r < 4; ++r) {
        float ob = __shfl_xor(best[g][r], m);
        int   oi = __shfl_xor(bidx[g][r], m);
        if (ob > best[g][r] || (ob == best[g][r] && oi < bidx[g][r])) {
          best[g][r] = ob; bidx[g][r] = oi;
        }
      }
  if (c == 0) {
    #pragma unroll
    for (int g = 0; g < 4; ++g)
      #pragma unroll
      for (int r = 0; r < 4; ++r) {
        int row = rowbase + g * 16 + q * 4 + r;
        best_part[(size_t)row * NSPLIT + ns] = best[g][r];
        idx_part [(size_t)row * NSPLIT + ns] = bidx[g][r];
      }
  }
}

// ---------------- kernel 3: merge + gather + fused loss (atomic/block) -------
// 32 rows/block. loss per row = ||xn||^2 - 2*t_best.
__global__ __launch_bounds__(256) void gather_loss_kernel(
    const float* __restrict__ cb, const float* __restrict__ best_part,
    const int* __restrict__ idx_part, const float* __restrict__ x2g,
    float* __restrict__ out_q, float* __restrict__ out_ind,
    float* __restrict__ out_loss)
{
  __shared__ int   sidx[32];
  __shared__ float sloss[32];
  int tid = threadIdx.x;
  int rb = blockIdx.x * 32;
  int r = tid >> 3, k = tid & 7;
  int row = rb + r;

  float b  = best_part[(size_t)row * NSPLIT + k];
  int   bi = idx_part [(size_t)row * NSPLIT + k];
  #pragma unroll
  for (int m = 1; m < 8; m <<= 1) {
    float ob = __shfl_xor(b, m);
    int   oi = __shfl_xor(bi, m);
    if (ob > b || (ob == b && oi < bi)) { b = ob; bi = oi; }
  }
  if (k == 0) {
    sidx[r] = bi;
    out_ind[row] = (float)bi;
    sloss[r] = x2g[row] - 2.0f * b;
  }
  __syncthreads();

  if (tid < 32) {
    float sl = sloss[tid];
    #pragma unroll
    for (int m = 1; m < 32; m <<= 1) sl += __shfl_xor(sl, m);
    if (tid == 0) atomicAdd(out_loss, sl * LOSS_SCALE);
  }

  // copy 32 codebook rows (512B each) to out_q
  const float4* cb4 = (const float4*)cb;
  float4* oq4 = (float4*)out_q;
  #pragma unroll
  for (int it = 0; it < 4; ++it) {
    int idx = it * 256 + tid;          // 0..1023
    int r2 = idx >> 5, c4 = idx & 31;
    oq4[(size_t)(rb + r2) * 32 + c4] = cb4[(size_t)sidx[r2] * 32 + c4];
  }
}

extern "C" void kernel_launch(void* const* d_in, const int* in_sizes, int n_in,
                              void* d_out, int out_size, void* d_ws, size_t ws_size,
                              hipStream_t stream)
{
  const float* x  = (const float*)d_in[0];   // [4,4096,128] fp32
  const float* cb = (const float*)d_in[1];   // [8192,128]  fp32

  char* ws = (char*)d_ws;
  _Float16* ehg      = (_Float16*)(ws + 0);          // 2 MB
  _Float16* elg      = (_Float16*)(ws + 2097152);    // 2 MB
  float*    e2g      = (float*)   (ws + 4194304);    // 32 KB (-e2/2)
  float*    best_part= (float*)   (ws + 4227072);    // 512 KB
  int*      idx_part = (int*)     (ws + 4751360);    // 512 KB
  float*    x2g      = (float*)   (ws + 5275648);    // 64 KB

  float* out_q    = (float*)d_out;                   // 16384*128
  float* out_ind  = out_q + (size_t)ROWS * DIM;      // 16384 (as float)
  float* out_loss = out_ind + ROWS;                  // 1

  prep_codebook<<<KCODES / 4, 256, 0, stream>>>(cb, ehg, elg, e2g, out_loss);
  argmin_kernel<<<(ROWS / MTILE) * NSPLIT, 256, 0, stream>>>(x, ehg, elg, e2g, best_part, idx_part, x2g);
  gather_loss_kernel<<<ROWS / 32, 256, 0, stream>>>(cb, best_part, idx_part, x2g, out_q, out_ind, out_loss);
}